// Round 7
// baseline (1400.100 us; speedup 1.0000x reference)
//
#include <hip/hip_runtime.h>

typedef _Float16 f16;
typedef __attribute__((ext_vector_type(8))) _Float16 f16x8;
typedef __attribute__((ext_vector_type(4))) float f32x4;

__device__ inline ushort f2h_bits(float f) {
    f16 h = (f16)f;
    return __builtin_bit_cast(ushort, h);
}

// ---------------------------------------------------------------------------
// Batched weight transpose+convert: W[K,N] f32 -> Wt[N,K] f16, 6 weights.
// ---------------------------------------------------------------------------
struct T6 {
    const float* s[6];
    ushort* d[6];
    int N[6];
};

__global__ __launch_bounds__(256) void transpose6_k(T6 a) {
    __shared__ ushort tile[32][33];
    const int z = blockIdx.z;
    const int K = 256, N = a.N[z];
    int k0 = blockIdx.x * 32, n0 = blockIdx.y * 32;
    if (n0 >= N) return;
    const float* W = a.s[z];
    ushort* Wt = a.d[z];
    int tx = threadIdx.x & 31, ty = threadIdx.x >> 5;
    #pragma unroll
    for (int i = 0; i < 32; i += 8)
        tile[ty + i][tx] = f2h_bits(W[(size_t)(k0 + ty + i) * N + n0 + tx]);
    __syncthreads();
    #pragma unroll
    for (int i = 0; i < 32; i += 8)
        Wt[(size_t)(n0 + ty + i) * K + k0 + tx] = tile[tx][ty + i];
}

// ---------------------------------------------------------------------------
// Batched CSR build (4 graphs), two-level binned (buckets of 256 rows).
// ---------------------------------------------------------------------------
struct GraphDesc {
    const int* ei;
    const float* w;
    int E, n, NB, bstoff;
    int* row_ptr;
    int2* perm;
};
struct G4 { GraphDesc g[4]; };

__global__ __launch_bounds__(256) void hist_b(G4 a, int* __restrict__ bcounts) {
    const GraphDesc& G = a.g[blockIdx.y];
    const int e0 = blockIdx.x * 4096;
    if (e0 >= G.E) return;
    __shared__ int h[512];
    int t = threadIdx.x;
    h[t] = 0; h[t + 256] = 0;
    __syncthreads();
    #pragma unroll
    for (int k = 0; k < 16; ++k) {
        int i = e0 + t + k * 256;
        if (i < G.E) atomicAdd(&h[((uint)G.ei[i]) >> 8], 1);
    }
    __syncthreads();
    int* bc = bcounts + blockIdx.y * 512;
    for (int b = t; b < 512; b += 256)
        if (h[b]) atomicAdd(&bc[b], h[b]);
}

__global__ __launch_bounds__(256) void scan_b(G4 a, const int* __restrict__ bcounts,
                                              int* __restrict__ bbase, int* __restrict__ bcursor) {
    const int gidx = blockIdx.x;
    const GraphDesc& G = a.g[gidx];
    const int* bc = bcounts + gidx * 512;
    int* base = bbase + gidx * 513;
    int* cur  = bcursor + gidx * 512;
    int t = threadIdx.x, lane = t & 63, wave = t >> 6;
    int v0 = bc[2 * t], v1 = bc[2 * t + 1];
    int s = v0 + v1;
    int incl = s;
    for (int off = 1; off < 64; off <<= 1) {
        int u = __shfl_up(incl, off);
        if (lane >= off) incl += u;
    }
    __shared__ int wsum[4];
    if (lane == 63) wsum[wave] = incl;
    __syncthreads();
    int excl = incl - s;
    for (int wv = 0; wv < wave; ++wv) excl += wsum[wv];
    base[2 * t] = excl;      cur[2 * t] = excl;
    base[2 * t + 1] = excl + v0; cur[2 * t + 1] = excl + v0;
    if (t == 0) { base[512] = G.E; G.row_ptr[G.n] = G.E; }
}

__global__ __launch_bounds__(256) void scatter_b(G4 a, int* __restrict__ bcursor,
                                                 int2* __restrict__ bst) {
    const GraphDesc& G = a.g[blockIdx.y];
    const int e0 = blockIdx.x * 4096;
    if (e0 >= G.E) return;
    __shared__ int hist[512], excl[512], sbase[512], lcur[512];
    __shared__ int2 stage[4096];
    __shared__ ushort sbin[4096];
    const int t = threadIdx.x, lane = t & 63, wave = t >> 6;
    const int cnt = min(4096, G.E - e0);
    int* bcur = bcursor + blockIdx.y * 512;

    hist[t] = 0; hist[t + 256] = 0;
    __syncthreads();

    int   d[16], s[16];
    float wv[16];
    #pragma unroll
    for (int k = 0; k < 16; ++k) {
        int i = t + k * 256;
        if (i < cnt) {
            d[k]  = G.ei[e0 + i];
            s[k]  = G.ei[(size_t)G.E + e0 + i];
            wv[k] = G.w[e0 + i];
            atomicAdd(&hist[((uint)d[k]) >> 8], 1);
        }
    }
    __syncthreads();

    {
        int v0 = hist[2 * t], v1 = hist[2 * t + 1];
        int sum = v0 + v1;
        int incl = sum;
        for (int off = 1; off < 64; off <<= 1) {
            int u = __shfl_up(incl, off);
            if (lane >= off) incl += u;
        }
        __shared__ int wsum[4];
        if (lane == 63) wsum[wave] = incl;
        __syncthreads();
        int e = incl - sum;
        for (int wvv = 0; wvv < wave; ++wvv) e += wsum[wvv];
        excl[2 * t] = e; excl[2 * t + 1] = e + v0;
    }
    __syncthreads();

    for (int b = t; b < 512; b += 256) {
        int c = hist[b];
        sbase[b] = c ? atomicAdd(&bcur[b], c) : 0;
        lcur[b] = excl[b];
    }
    __syncthreads();

    #pragma unroll
    for (int k = 0; k < 16; ++k) {
        int i = t + k * 256;
        if (i < cnt) {
            int bin = ((uint)d[k]) >> 8;
            int pos = atomicAdd(&lcur[bin], 1);
            stage[pos] = make_int2((s[k] << 8) | (d[k] & 255), __float_as_int(wv[k]));
            sbin[pos] = (ushort)bin;
        }
    }
    __syncthreads();

    #pragma unroll
    for (int k = 0; k < 16; ++k) {
        int i = t + k * 256;
        if (i < cnt) {
            int2 r = stage[i];
            int bin = sbin[i];
            bst[(size_t)G.bstoff + sbase[bin] + i - excl[bin]] = r;
        }
    }
}

__global__ __launch_bounds__(256) void finalize_b(G4 a, const int* __restrict__ bbase,
                                                  const int2* __restrict__ bst) {
    const GraphDesc& G = a.g[blockIdx.y];
    const int b = blockIdx.x;
    if (b >= G.NB) return;
    __shared__ int hist[256], cur[256], wsum[4];
    const int t = threadIdx.x, lane = t & 63, wave = t >> 6;
    const int* base = bbase + blockIdx.y * 513;
    const int lo = base[b], hi = base[b + 1];
    const int2* bg = bst + G.bstoff;
    hist[t] = 0;
    __syncthreads();
    for (int i = lo + t; i < hi; i += 256)
        atomicAdd(&hist[bg[i].x & 255], 1);
    __syncthreads();
    int v = hist[t];
    int incl = v;
    for (int off = 1; off < 64; off <<= 1) {
        int u = __shfl_up(incl, off);
        if (lane >= off) incl += u;
    }
    if (lane == 63) wsum[wave] = incl;
    __syncthreads();
    int excl = incl - v;
    for (int wv = 0; wv < wave; ++wv) excl += wsum[wv];
    const int r0 = b << 8;
    const int nrows = min(256, G.n - r0);
    if (t < nrows) G.row_ptr[r0 + t] = lo + excl;
    cur[t] = lo + excl;
    __syncthreads();
    for (int i = lo + t; i < hi; i += 256) {
        int2 r = bg[i];
        int local = r.x & 255;
        int slot = atomicAdd(&cur[local], 1);
        G.perm[slot] = make_int2(r.x >> 8, r.y);
    }
}

// ---------------------------------------------------------------------------
// SpMM bodies
// ---------------------------------------------------------------------------
struct PairA {             // L1: two graphs gather from same table, relu+bias, f16 out
    const f16* x;
    const int2* perm[2];
    const int* rp[2];
    ushort* outh[2];
    const float* bias;
    int n, gx;             // gx = ceil(n/4); blocks = 2*gx
};

struct L2A {               // L2: two graphs, separate tables, bias, f16+f32 out
    const f16* x[2];
    const int2* perm[2];
    const int* rp[2];
    ushort* outh[2];
    float* outf[2];
    const float* bias;
    int n, gx;
};

__device__ __forceinline__ void spmm_pair_body(const PairA& a, int sb) {
    const int g = sb / a.gx;
    const int rb = sb % a.gx;
    const int wave = threadIdx.x >> 6, lane = threadIdx.x & 63;
    const int row = rb * 4 + wave;
    if (row >= a.n) return;
    const int2* __restrict__ perm = a.perm[g];
    const int*  __restrict__ rp   = a.rp[g];
    const int F = 256;
    const int e0 = rp[row], e1 = rp[row + 1];
    float acc[4] = {};
    const int laneoff = lane * 4;

    for (int eb = e0; eb < e1; eb += 64) {
        int idx = eb + lane;
        int myS = 0; int myW = 0;
        if (idx < e1) { int2 rec = perm[idx]; myS = rec.x; myW = rec.y; }
        int m = min(64, e1 - eb);
        for (int j0 = 0; j0 < m; j0 += 8) {
            #pragma unroll
            for (int u = 0; u < 8; ++u) {
                int j = j0 + u;   // padded lanes carry w=0
                int   s = __builtin_amdgcn_readlane(myS, j);
                float w = __int_as_float(__builtin_amdgcn_readlane(myW, j));
                const f16* xr = a.x + (size_t)((uint)s * (uint)F) + laneoff;
                union { uint2 u2; f16 h[4]; } cv;
                cv.u2 = *reinterpret_cast<const uint2*>(xr);
                acc[0] = fmaf((float)cv.h[0], w, acc[0]);
                acc[1] = fmaf((float)cv.h[1], w, acc[1]);
                acc[2] = fmaf((float)cv.h[2], w, acc[2]);
                acc[3] = fmaf((float)cv.h[3], w, acc[3]);
            }
        }
    }

    #pragma unroll
    for (int c = 0; c < 4; ++c)
        acc[c] = fmaxf(acc[c] + a.bias[laneoff + c], 0.f);
    *reinterpret_cast<ushort4*>(a.outh[g] + (size_t)row * F + laneoff) =
        make_ushort4(f2h_bits(acc[0]), f2h_bits(acc[1]), f2h_bits(acc[2]), f2h_bits(acc[3]));
}

__device__ __forceinline__ void spmm_l2_body(const L2A& a, int sb) {
    const int g = sb / a.gx;
    const int rb = sb % a.gx;
    const int wave = threadIdx.x >> 6, lane = threadIdx.x & 63;
    const int row = rb * 4 + wave;
    if (row >= a.n) return;
    const f16*  __restrict__ x    = a.x[g];
    const int2* __restrict__ perm = a.perm[g];
    const int*  __restrict__ rp   = a.rp[g];
    const int F = 128;
    const int e0 = rp[row], e1 = rp[row + 1];
    float acc[2] = {};
    const int laneoff = lane * 2;

    for (int eb = e0; eb < e1; eb += 64) {
        int idx = eb + lane;
        int myS = 0; int myW = 0;
        if (idx < e1) { int2 rec = perm[idx]; myS = rec.x; myW = rec.y; }
        int m = min(64, e1 - eb);
        for (int j0 = 0; j0 < m; j0 += 8) {
            #pragma unroll
            for (int u = 0; u < 8; ++u) {
                int j = j0 + u;
                int   s = __builtin_amdgcn_readlane(myS, j);
                float w = __int_as_float(__builtin_amdgcn_readlane(myW, j));
                union { uint u1; f16 h[2]; } cv;
                cv.u1 = *reinterpret_cast<const uint*>(x + (size_t)((uint)s * (uint)F) + laneoff);
                acc[0] = fmaf((float)cv.h[0], w, acc[0]);
                acc[1] = fmaf((float)cv.h[1], w, acc[1]);
            }
        }
    }

    acc[0] += a.bias[laneoff];
    acc[1] += a.bias[laneoff + 1];
    size_t ob = (size_t)row * F + laneoff;
    *reinterpret_cast<float2*>(a.outf[g] + ob) = make_float2(acc[0], acc[1]);
    *reinterpret_cast<ushort2*>(a.outh[g] + ob) = make_ushort2(f2h_bits(acc[0]), f2h_bits(acc[1]));
}

// ---------------------------------------------------------------------------
// f16 MFMA GEMM body: C[M,N] = A[M,K] @ Bt[N,K]^T, 128x128 tile, 4 waves.
// ---------------------------------------------------------------------------
struct GemmJob {
    const void* A;
    const ushort* A2;
    const ushort* Bt;
    const float* bias;
    ushort* Ch;
    float* Cf;
    int M, N, K, Nb;       // Nb = N/128 (grid columns, N-fastest)
};

template<bool CVTA, bool FUSE, bool RELU, bool BIAS, bool F32OUT>
__device__ __forceinline__ void gemm_body(const GemmJob& j, int bm128, int bn128) {
    __shared__ ushort Asb[128 * 32];
    __shared__ ushort Bsb[128 * 32];
    const int tid = threadIdx.x;
    const int lane = tid & 63, wave = tid >> 6;
    const int wr = wave >> 1, wc = wave & 1;
    const int bm = bm128 * 128, bn = bn128 * 128;
    const int M = j.M, N = j.N, K = j.K;

    f32x4 acc[4][4] = {};

    for (int k0 = 0; k0 < K; k0 += 32) {
        #pragma unroll
        for (int h = 0; h < 2; ++h) {
            int slot = tid + 256 * h;
            int r = slot >> 2, cb = slot & 3;
            int row = bm + r;
            uint4 v = make_uint4(0, 0, 0, 0);
            if (row < M) {
                int kk = k0 + cb * 8;
                if (CVTA) {
                    const float* Af = (const float*)j.A;
                    float4 lo = *reinterpret_cast<const float4*>(Af + (size_t)row * K + kk);
                    float4 hi = *reinterpret_cast<const float4*>(Af + (size_t)row * K + kk + 4);
                    ushort h8[8] = { f2h_bits(lo.x), f2h_bits(lo.y), f2h_bits(lo.z), f2h_bits(lo.w),
                                     f2h_bits(hi.x), f2h_bits(hi.y), f2h_bits(hi.z), f2h_bits(hi.w) };
                    v = *reinterpret_cast<const uint4*>(h8);
                } else if (FUSE) {
                    const ushort* Ap = (kk < 128) ? (const ushort*)j.A : j.A2;
                    v = *reinterpret_cast<const uint4*>(Ap + (size_t)row * 128 + (kk & 127));
                } else {
                    v = *reinterpret_cast<const uint4*>((const ushort*)j.A + (size_t)row * K + kk);
                }
            }
            int scb = cb ^ ((r >> 1) & 3);
            *reinterpret_cast<uint4*>(&Asb[r * 32 + scb * 8]) = v;
        }
        #pragma unroll
        for (int h = 0; h < 2; ++h) {
            int slot = tid + 256 * h;
            int r = slot >> 2, cb = slot & 3;
            uint4 v = *reinterpret_cast<const uint4*>(j.Bt + (size_t)(bn + r) * K + k0 + cb * 8);
            int scb = cb ^ ((r >> 1) & 3);
            *reinterpret_cast<uint4*>(&Bsb[r * 32 + scb * 8]) = v;
        }
        __syncthreads();

        f16x8 fa[4], fb[4];
        #pragma unroll
        for (int i = 0; i < 4; ++i) {
            int r = wr * 64 + i * 16 + (lane & 15);
            int scb = (lane >> 4) ^ ((r >> 1) & 3);
            fa[i] = *reinterpret_cast<const f16x8*>(&Asb[r * 32 + scb * 8]);
        }
        #pragma unroll
        for (int jj = 0; jj < 4; ++jj) {
            int r = wc * 64 + jj * 16 + (lane & 15);
            int scb = (lane >> 4) ^ ((r >> 1) & 3);
            fb[jj] = *reinterpret_cast<const f16x8*>(&Bsb[r * 32 + scb * 8]);
        }
        #pragma unroll
        for (int i = 0; i < 4; ++i)
            #pragma unroll
            for (int jj = 0; jj < 4; ++jj)
                acc[i][jj] = __builtin_amdgcn_mfma_f32_16x16x32_f16(fa[i], fb[jj], acc[i][jj], 0, 0, 0);
        __syncthreads();
    }

    #pragma unroll
    for (int i = 0; i < 4; ++i) {
        #pragma unroll
        for (int r4 = 0; r4 < 4; ++r4) {
            int row = bm + wr * 64 + i * 16 + (lane >> 4) * 4 + r4;
            if (row >= M) continue;
            #pragma unroll
            for (int jj = 0; jj < 4; ++jj) {
                int col = bn + wc * 64 + jj * 16 + (lane & 15);
                float v = acc[i][jj][r4];
                if (BIAS) v += j.bias[col];
                if (RELU) v = fmaxf(v, 0.f);
                if (F32OUT) j.Cf[(size_t)row * N + col] = v;
                else        j.Ch[(size_t)row * N + col] = f2h_bits(v);
            }
        }
    }
}

// ---------------------------------------------------------------------------
// Standalone kernels
// ---------------------------------------------------------------------------
template<bool CVTA, bool FUSE, bool RELU, bool BIAS, bool F32OUT>
__global__ __launch_bounds__(256) void gemm_k(GemmJob j) {
    int bx = blockIdx.x;
    gemm_body<CVTA, FUSE, RELU, BIAS, F32OUT>(j, bx / j.Nb, bx % j.Nb);
}

__global__ __launch_bounds__(256) void spmm_pair_k(PairA a) {
    spmm_pair_body(a, blockIdx.x);
}

__global__ __launch_bounds__(256) void spmm_l2_k(L2A a) {
    spmm_l2_body(a, blockIdx.x);
}

// ---------------------------------------------------------------------------
// Fat kernels: gemm blocks first (dispatch early), spmm blocks fill the rest.
// SM: 0=pair L1, 1=dual L2.  GM: 0=CVTA plain, 1=plain, 2=fusion.
// ---------------------------------------------------------------------------
struct FatA {
    PairA pa;
    L2A la;
    int spmm_blocks;
    GemmJob j0, j1;
    int jb0, jb1;
};

template<int SM, int GM>
__global__ __launch_bounds__(256, 4) void fat_k(FatA a) {
    int bx = blockIdx.x;
    int gtot = a.jb0 + a.jb1;
    if (bx < gtot) {
        const GemmJob& j = (bx < a.jb0) ? a.j0 : a.j1;
        int gb = (bx < a.jb0) ? bx : bx - a.jb0;
        gemm_body<(GM == 0), (GM == 2), (GM == 2), (GM == 2), (GM == 2)>(j, gb / j.Nb, gb % j.Nb);
    } else {
        int sb = bx - gtot;
        if (SM == 0) spmm_pair_body(a.pa, sb);
        else         spmm_l2_body(a.la, sb);
    }
}

// ---------------------------------------------------------------------------
// Orchestration
// ---------------------------------------------------------------------------
extern "C" void kernel_launch(void* const* d_in, const int* in_sizes, int n_in,
                              void* d_out, int out_size, void* d_ws, size_t ws_size,
                              hipStream_t stream) {
    const float* Xd       = (const float*)d_in[0];
    const int*   eid_sim  = (const int*)  d_in[1];
    const float* wd_sim   = (const float*)d_in[2];
    const int*   eid_feat = (const int*)  d_in[3];
    const float* wd_feat  = (const float*)d_in[4];
    const float* Xs       = (const float*)d_in[5];
    const int*   eis_sim  = (const int*)  d_in[6];
    const float* ws_sim   = (const float*)d_in[7];
    const int*   eis_feat = (const int*)  d_in[8];
    const float* ws_feat  = (const float*)d_in[9];
    const float* W1d = (const float*)d_in[10]; const float* b1d = (const float*)d_in[11];
    const float* W2d = (const float*)d_in[12]; const float* b2d = (const float*)d_in[13];
    const float* W1s = (const float*)d_in[14]; const float* b1s = (const float*)d_in[15];
    const float* W2s = (const float*)d_in[16]; const float* b2s = (const float*)d_in[17];
    const float* Wfd = (const float*)d_in[18]; const float* bfd = (const float*)d_in[19];
    const float* Wfs = (const float*)d_in[20]; const float* bfs = (const float*)d_in[21];

    const int Fd = 256, H2 = 128;
    const int Nd = in_sizes[0] / Fd;
    const int Ns = in_sizes[5] / Fd;
    const int Ed = in_sizes[2];
    const int Es = in_sizes[7];

    float* out    = (float*)d_out;
    float* o_emb1 = out;
    float* o_emb2 = o_emb1 + (size_t)Nd * H2;
    float* o_e1s  = o_emb2 + (size_t)Ns * H2;
    float* o_e1f  = o_e1s  + (size_t)Nd * H2;
    float* o_e2s  = o_e1f  + (size_t)Nd * H2;
    float* o_e2f  = o_e2s  + (size_t)Ns * H2;

    char* p = (char*)d_ws;
    auto alloc = [&](size_t bytes) { char* q = p; p += (bytes + 255) & ~(size_t)255; return q; };

    // ---- common allocations ----
    ushort* W1dt  = (ushort*)alloc(256 * 256 * 2);
    ushort* W2dt  = (ushort*)alloc(256 * 128 * 2);
    ushort* Wfdt  = (ushort*)alloc(256 * 128 * 2);
    ushort* W1st  = (ushort*)alloc(256 * 256 * 2);
    ushort* W2st  = (ushort*)alloc(256 * 128 * 2);
    ushort* Wfst  = (ushort*)alloc(256 * 128 * 2);
    int2*   perm0 = (int2*)alloc((size_t)Ed * 8);
    int2*   perm1 = (int2*)alloc((size_t)Ed * 8);
    int2*   perm2 = (int2*)alloc((size_t)Es * 8);
    int2*   perm3 = (int2*)alloc((size_t)Es * 8);
    int*    rp0   = (int*) alloc((size_t)(Nd + 1) * 4);
    int*    rp1   = (int*) alloc((size_t)(Nd + 1) * 4);
    int*    rp2   = (int*) alloc((size_t)(Ns + 1) * 4);
    int*    rp3   = (int*) alloc((size_t)(Ns + 1) * 4);
    int*    bcounts = (int*)alloc(4 * 512 * 4);
    int*    bbase   = (int*)alloc(4 * 513 * 4);
    int*    bcursor = (int*)alloc(4 * 512 * 4);
    // sequential-path buffers (also drug buffers in overlap path)
    ushort* xw1d  = (ushort*)alloc((size_t)Nd * 256 * 2);
    ushort* hbuf0 = (ushort*)alloc((size_t)Nd * 256 * 2);
    ushort* hbuf1 = (ushort*)alloc((size_t)Nd * 256 * 2);
    ushort* tbuf0 = (ushort*)alloc((size_t)Nd * 128 * 2);
    ushort* tbuf1 = (ushort*)alloc((size_t)Nd * 128 * 2);
    size_t seq_need = (size_t)(p - (char*)d_ws);
    // overlap-path extra buffers (disease branch live concurrently)
    ushort* xw1s   = (ushort*)alloc((size_t)Ns * 256 * 2);
    ushort* hbuf0s = (ushort*)alloc((size_t)Ns * 256 * 2);
    ushort* hbuf1s = (ushort*)alloc((size_t)Ns * 256 * 2);
    ushort* tbuf0s = (ushort*)alloc((size_t)Ns * 128 * 2);
    ushort* tbuf1s = (ushort*)alloc((size_t)Ns * 128 * 2);
    size_t ovl_need = (size_t)(p - (char*)d_ws);
    const bool OVL = (ovl_need <= ws_size);

    int2* bst = (int2*)hbuf0;   // CSR staging aliases hbuf0+hbuf1 (dead during build)

    const int Mb_d = (Nd + 127) / 128, Mb_s = (Ns + 127) / 128;
    const int gx_d = (Nd + 3) / 4,     gx_s = (Ns + 3) / 4;

    // ---- batched weight transposes ----
    {
        T6 a;
        a.s[0] = W1d; a.s[1] = W2d; a.s[2] = Wfd; a.s[3] = W1s; a.s[4] = W2s; a.s[5] = Wfs;
        a.d[0] = W1dt; a.d[1] = W2dt; a.d[2] = Wfdt; a.d[3] = W1st; a.d[4] = W2st; a.d[5] = Wfst;
        a.N[0] = 256; a.N[1] = 128; a.N[2] = 128; a.N[3] = 256; a.N[4] = 128; a.N[5] = 128;
        transpose6_k<<<dim3(8, 8, 6), 256, 0, stream>>>(a);
    }

    // ---- batched CSR build ----
    G4 a;
    a.g[0] = { eid_sim,  wd_sim,  Ed, Nd, (Nd + 255) >> 8, 0,           rp0, perm0 };
    a.g[1] = { eid_feat, wd_feat, Ed, Nd, (Nd + 255) >> 8, Ed,          rp1, perm1 };
    a.g[2] = { eis_sim,  ws_sim,  Es, Ns, (Ns + 255) >> 8, 2 * Ed,      rp2, perm2 };
    a.g[3] = { eis_feat, ws_feat, Es, Ns, (Ns + 255) >> 8, 2 * Ed + Es, rp3, perm3 };
    {
        const int maxEB = (Ed + 4095) / 4096;
        const int maxNB = (Nd + 255) >> 8;
        hipMemsetAsync(bcounts, 0, 4 * 512 * 4, stream);
        hist_b<<<dim3(maxEB, 4), 256, 0, stream>>>(a, bcounts);
        scan_b<<<4, 256, 0, stream>>>(a, bcounts, bbase, bcursor);
        scatter_b<<<dim3(maxEB, 4), 256, 0, stream>>>(a, bcursor, bst);
        finalize_b<<<dim3(maxNB, 4), 256, 0, stream>>>(a, bbase, bst);
    }

    auto mkjob = [](const void* A, const ushort* A2, const ushort* Bt, const float* bias,
                    ushort* Ch, float* Cf, int M, int N, int K) {
        GemmJob j; j.A = A; j.A2 = A2; j.Bt = Bt; j.bias = bias;
        j.Ch = Ch; j.Cf = Cf; j.M = M; j.N = N; j.K = K; j.Nb = N / 128; return j;
    };

    if (OVL) {
        // es/ef alias xw1 buffers (dead after the corresponding L1 spmm)
        ushort* es_d = xw1d;  ushort* ef_d = xw1d + (size_t)Nd * 128;
        ushort* es_s = xw1s;  ushort* ef_s = xw1s + (size_t)Ns * 128;

        // 1. drug xw1 GEMM
        gemm_k<true, false, false, false, false><<<2 * Mb_d, 256, 0, stream>>>(
            mkjob(Xd, nullptr, W1dt, nullptr, xw1d, nullptr, Nd, 256, 256));

        FatA f;
        // 2. drug L1 pair spmm  ||  disease xw1 GEMM
        f = FatA{};
        f.pa.x = (const f16*)xw1d;
        f.pa.perm[0] = perm0; f.pa.perm[1] = perm1;
        f.pa.rp[0] = rp0; f.pa.rp[1] = rp1;
        f.pa.outh[0] = hbuf0; f.pa.outh[1] = hbuf1;
        f.pa.bias = b1d; f.pa.n = Nd; f.pa.gx = gx_d;
        f.spmm_blocks = 2 * gx_d;
        f.j0 = mkjob(Xs, nullptr, W1st, nullptr, xw1s, nullptr, Ns, 256, 256);
        f.jb0 = 2 * Mb_s; f.jb1 = 0; f.j1 = f.j0;
        fat_k<0, 0><<<f.jb0 + f.spmm_blocks, 256, 0, stream>>>(f);

        // 3. disease L1 pair spmm  ||  drug W2 GEMM x2
        f = FatA{};
        f.pa.x = (const f16*)xw1s;
        f.pa.perm[0] = perm2; f.pa.perm[1] = perm3;
        f.pa.rp[0] = rp2; f.pa.rp[1] = rp3;
        f.pa.outh[0] = hbuf0s; f.pa.outh[1] = hbuf1s;
        f.pa.bias = b1s; f.pa.n = Ns; f.pa.gx = gx_s;
        f.spmm_blocks = 2 * gx_s;
        f.j0 = mkjob(hbuf0, nullptr, W2dt, nullptr, tbuf0, nullptr, Nd, 128, 256);
        f.j1 = mkjob(hbuf1, nullptr, W2dt, nullptr, tbuf1, nullptr, Nd, 128, 256);
        f.jb0 = Mb_d; f.jb1 = Mb_d;
        fat_k<0, 1><<<f.jb0 + f.jb1 + f.spmm_blocks, 256, 0, stream>>>(f);

        // 4. drug L2 spmm x2  ||  disease W2 GEMM x2
        f = FatA{};
        f.la.x[0] = (const f16*)tbuf0; f.la.x[1] = (const f16*)tbuf1;
        f.la.perm[0] = perm0; f.la.perm[1] = perm1;
        f.la.rp[0] = rp0; f.la.rp[1] = rp1;
        f.la.outh[0] = es_d; f.la.outh[1] = ef_d;
        f.la.outf[0] = o_e1s; f.la.outf[1] = o_e1f;
        f.la.bias = b2d; f.la.n = Nd; f.la.gx = gx_d;
        f.spmm_blocks = 2 * gx_d;
        f.j0 = mkjob(hbuf0s, nullptr, W2st, nullptr, tbuf0s, nullptr, Ns, 128, 256);
        f.j1 = mkjob(hbuf1s, nullptr, W2st, nullptr, tbuf1s, nullptr, Ns, 128, 256);
        f.jb0 = Mb_s; f.jb1 = Mb_s;
        fat_k<1, 1><<<f.jb0 + f.jb1 + f.spmm_blocks, 256, 0, stream>>>(f);

        // 5. disease L2 spmm x2  ||  drug fusion GEMM
        f = FatA{};
        f.la.x[0] = (const f16*)tbuf0s; f.la.x[1] = (const f16*)tbuf1s;
        f.la.perm[0] = perm2; f.la.perm[1] = perm3;
        f.la.rp[0] = rp2; f.la.rp[1] = rp3;
        f.la.outh[0] = es_s; f.la.outh[1] = ef_s;
        f.la.outf[0] = o_e2s; f.la.outf[1] = o_e2f;
        f.la.bias = b2s; f.la.n = Ns; f.la.gx = gx_s;
        f.spmm_blocks = 2 * gx_s;
        f.j0 = mkjob(es_d, ef_d, Wfdt, bfd, nullptr, o_emb1, Nd, 128, 256);
        f.jb0 = Mb_d; f.jb1 = 0; f.j1 = f.j0;
        fat_k<1, 2><<<f.jb0 + f.spmm_blocks, 256, 0, stream>>>(f);

        // 6. disease fusion GEMM
        gemm_k<false, true, true, true, true><<<Mb_s, 256, 0, stream>>>(
            mkjob(es_s, ef_s, Wfst, bfs, nullptr, o_emb2, Ns, 128, 256));
    } else {
        // sequential fallback (round-6 schedule, shared buffers per branch)
        auto branch = [&](const float* X, int n, int gx, int Mb,
                          const int2* pA, const int* rpA,
                          const int2* pB, const int* rpB,
                          const ushort* W1t, const float* b1,
                          const ushort* W2t, const float* b2,
                          const ushort* Wft, const float* bfu,
                          float* o_sim, float* o_feat, float* o_emb) {
            ushort* es_h = xw1d;
            ushort* ef_h = xw1d + (size_t)n * 128;
            gemm_k<true, false, false, false, false><<<2 * Mb, 256, 0, stream>>>(
                mkjob(X, nullptr, W1t, nullptr, xw1d, nullptr, n, 256, 256));
            PairA pa;
            pa.x = (const f16*)xw1d;
            pa.perm[0] = pA; pa.perm[1] = pB;
            pa.rp[0] = rpA;  pa.rp[1] = rpB;
            pa.outh[0] = hbuf0; pa.outh[1] = hbuf1;
            pa.bias = b1; pa.n = n; pa.gx = gx;
            spmm_pair_k<<<2 * gx, 256, 0, stream>>>(pa);
            gemm_k<false, false, false, false, false><<<Mb, 256, 0, stream>>>(
                mkjob(hbuf0, nullptr, W2t, nullptr, tbuf0, nullptr, n, 128, 256));
            gemm_k<false, false, false, false, false><<<Mb, 256, 0, stream>>>(
                mkjob(hbuf1, nullptr, W2t, nullptr, tbuf1, nullptr, n, 128, 256));
            L2A la;
            la.x[0] = (const f16*)tbuf0; la.x[1] = (const f16*)tbuf1;
            la.perm[0] = pA; la.perm[1] = pB;
            la.rp[0] = rpA;  la.rp[1] = rpB;
            la.outh[0] = es_h; la.outh[1] = ef_h;
            la.outf[0] = o_sim; la.outf[1] = o_feat;
            la.bias = b2; la.n = n; la.gx = gx;
            spmm_l2_k<<<2 * gx, 256, 0, stream>>>(la);
            gemm_k<false, true, true, true, true><<<Mb, 256, 0, stream>>>(
                mkjob(es_h, ef_h, Wft, bfu, nullptr, o_emb, n, 128, 256));
        };
        branch(Xd, Nd, gx_d, Mb_d, perm0, rp0, perm1, rp1,
               W1dt, b1d, W2dt, b2d, Wfdt, bfd, o_e1s, o_e1f, o_emb1);
        branch(Xs, Ns, gx_s, Mb_s, perm2, rp2, perm3, rp3,
               W1st, b1s, W2st, b2s, Wfst, bfs, o_e2s, o_e2f, o_emb2);
    }
    (void)seq_need;
}

// Round 8
// 1378.671 us; speedup vs baseline: 1.0155x; 1.0155x over previous
//
#include <hip/hip_runtime.h>

typedef _Float16 f16;
typedef __attribute__((ext_vector_type(8))) _Float16 f16x8;
typedef __attribute__((ext_vector_type(4))) float f32x4;

__device__ inline ushort f2h_bits(float f) {
    f16 h = (f16)f;
    return __builtin_bit_cast(ushort, h);
}

// ---------------------------------------------------------------------------
// Batched weight transpose+convert: W[K,N] f32 -> Wt[N,K] f16, 6 weights.
// ---------------------------------------------------------------------------
struct T6 {
    const float* s[6];
    ushort* d[6];
    int N[6];
};

__global__ __launch_bounds__(256) void transpose6_k(T6 a) {
    __shared__ ushort tile[32][33];
    const int z = blockIdx.z;
    const int K = 256, N = a.N[z];
    int k0 = blockIdx.x * 32, n0 = blockIdx.y * 32;
    if (n0 >= N) return;
    const float* W = a.s[z];
    ushort* Wt = a.d[z];
    int tx = threadIdx.x & 31, ty = threadIdx.x >> 5;
    #pragma unroll
    for (int i = 0; i < 32; i += 8)
        tile[ty + i][tx] = f2h_bits(W[(size_t)(k0 + ty + i) * N + n0 + tx]);
    __syncthreads();
    #pragma unroll
    for (int i = 0; i < 32; i += 8)
        Wt[(size_t)(n0 + ty + i) * K + k0 + tx] = tile[tx][ty + i];
}

// ---------------------------------------------------------------------------
// Batched CSR build (4 graphs), two-level binned (buckets of 256 rows).
// ---------------------------------------------------------------------------
struct GraphDesc {
    const int* ei;      // [2,E]: dst = ei[0..E), src = ei[E..2E)
    const float* w;
    int E, n, NB, bstoff;
    int* row_ptr;       // [n+1]
    int2* perm;         // [E] (src, w_bits)
};
struct G4 { GraphDesc g[4]; };

__global__ __launch_bounds__(256) void hist_b(G4 a, int* __restrict__ bcounts) {
    const GraphDesc& G = a.g[blockIdx.y];
    const int e0 = blockIdx.x * 4096;
    if (e0 >= G.E) return;
    __shared__ int h[512];
    int t = threadIdx.x;
    h[t] = 0; h[t + 256] = 0;
    __syncthreads();
    #pragma unroll
    for (int k = 0; k < 16; ++k) {
        int i = e0 + t + k * 256;
        if (i < G.E) atomicAdd(&h[((uint)G.ei[i]) >> 8], 1);
    }
    __syncthreads();
    int* bc = bcounts + blockIdx.y * 512;
    for (int b = t; b < 512; b += 256)
        if (h[b]) atomicAdd(&bc[b], h[b]);
}

__global__ __launch_bounds__(256) void scan_b(G4 a, const int* __restrict__ bcounts,
                                              int* __restrict__ bbase, int* __restrict__ bcursor) {
    const int gidx = blockIdx.x;
    const GraphDesc& G = a.g[gidx];
    const int* bc = bcounts + gidx * 512;
    int* base = bbase + gidx * 513;
    int* cur  = bcursor + gidx * 512;
    int t = threadIdx.x, lane = t & 63, wave = t >> 6;
    int v0 = bc[2 * t], v1 = bc[2 * t + 1];
    int s = v0 + v1;
    int incl = s;
    for (int off = 1; off < 64; off <<= 1) {
        int u = __shfl_up(incl, off);
        if (lane >= off) incl += u;
    }
    __shared__ int wsum[4];
    if (lane == 63) wsum[wave] = incl;
    __syncthreads();
    int excl = incl - s;
    for (int wv = 0; wv < wave; ++wv) excl += wsum[wv];
    base[2 * t] = excl;      cur[2 * t] = excl;
    base[2 * t + 1] = excl + v0; cur[2 * t + 1] = excl + v0;
    if (t == 0) { base[512] = G.E; G.row_ptr[G.n] = G.E; }
}

__global__ __launch_bounds__(256) void scatter_b(G4 a, int* __restrict__ bcursor,
                                                 int2* __restrict__ bst) {
    const GraphDesc& G = a.g[blockIdx.y];
    const int e0 = blockIdx.x * 4096;
    if (e0 >= G.E) return;
    __shared__ int hist[512], excl[512], sbase[512], lcur[512];
    __shared__ int2 stage[4096];
    __shared__ ushort sbin[4096];
    const int t = threadIdx.x, lane = t & 63, wave = t >> 6;
    const int cnt = min(4096, G.E - e0);
    int* bcur = bcursor + blockIdx.y * 512;

    hist[t] = 0; hist[t + 256] = 0;
    __syncthreads();

    int   d[16], s[16];
    float wv[16];
    #pragma unroll
    for (int k = 0; k < 16; ++k) {
        int i = t + k * 256;
        if (i < cnt) {
            d[k]  = G.ei[e0 + i];
            s[k]  = G.ei[(size_t)G.E + e0 + i];
            wv[k] = G.w[e0 + i];
            atomicAdd(&hist[((uint)d[k]) >> 8], 1);
        }
    }
    __syncthreads();

    {
        int v0 = hist[2 * t], v1 = hist[2 * t + 1];
        int sum = v0 + v1;
        int incl = sum;
        for (int off = 1; off < 64; off <<= 1) {
            int u = __shfl_up(incl, off);
            if (lane >= off) incl += u;
        }
        __shared__ int wsum[4];
        if (lane == 63) wsum[wave] = incl;
        __syncthreads();
        int e = incl - sum;
        for (int wvv = 0; wvv < wave; ++wvv) e += wsum[wvv];
        excl[2 * t] = e; excl[2 * t + 1] = e + v0;
    }
    __syncthreads();

    for (int b = t; b < 512; b += 256) {
        int c = hist[b];
        sbase[b] = c ? atomicAdd(&bcur[b], c) : 0;
        lcur[b] = excl[b];
    }
    __syncthreads();

    #pragma unroll
    for (int k = 0; k < 16; ++k) {
        int i = t + k * 256;
        if (i < cnt) {
            int bin = ((uint)d[k]) >> 8;
            int pos = atomicAdd(&lcur[bin], 1);
            stage[pos] = make_int2((s[k] << 8) | (d[k] & 255), __float_as_int(wv[k]));
            sbin[pos] = (ushort)bin;
        }
    }
    __syncthreads();

    #pragma unroll
    for (int k = 0; k < 16; ++k) {
        int i = t + k * 256;
        if (i < cnt) {
            int2 r = stage[i];
            int bin = sbin[i];
            bst[(size_t)G.bstoff + sbase[bin] + i - excl[bin]] = r;
        }
    }
}

__global__ __launch_bounds__(256) void finalize_b(G4 a, const int* __restrict__ bbase,
                                                  const int2* __restrict__ bst) {
    const GraphDesc& G = a.g[blockIdx.y];
    const int b = blockIdx.x;
    if (b >= G.NB) return;
    __shared__ int hist[256], cur[256], wsum[4];
    const int t = threadIdx.x, lane = t & 63, wave = t >> 6;
    const int* base = bbase + blockIdx.y * 513;
    const int lo = base[b], hi = base[b + 1];
    const int2* bg = bst + G.bstoff;
    hist[t] = 0;
    __syncthreads();
    for (int i = lo + t; i < hi; i += 256)
        atomicAdd(&hist[bg[i].x & 255], 1);
    __syncthreads();
    int v = hist[t];
    int incl = v;
    for (int off = 1; off < 64; off <<= 1) {
        int u = __shfl_up(incl, off);
        if (lane >= off) incl += u;
    }
    if (lane == 63) wsum[wave] = incl;
    __syncthreads();
    int excl = incl - v;
    for (int wv = 0; wv < wave; ++wv) excl += wsum[wv];
    const int r0 = b << 8;
    const int nrows = min(256, G.n - r0);
    if (t < nrows) G.row_ptr[r0 + t] = lo + excl;
    cur[t] = lo + excl;
    __syncthreads();
    for (int i = lo + t; i < hi; i += 256) {
        int2 r = bg[i];
        int local = r.x & 255;
        int slot = atomicAdd(&cur[local], 1);
        G.perm[slot] = make_int2(r.x >> 8, r.y);
    }
}

// ---------------------------------------------------------------------------
// Paired L1 SpMM: two edge sets gathering from the SAME table.
// blockIdx.y selects graph. out = relu(spmm + bias), f16.
// ---------------------------------------------------------------------------
struct PairDesc {
    const int2* perm[2];
    const int*  rp[2];
    ushort*     outh[2];
};

template<int C>
__global__ __launch_bounds__(256) void spmm_pair_f16(
    const f16* __restrict__ x, PairDesc a, const float* __restrict__ bias, int n)
{
    const int g = blockIdx.y;
    const int wave = threadIdx.x >> 6, lane = threadIdx.x & 63;
    const int row = blockIdx.x * 4 + wave;
    if (row >= n) return;
    const int2* __restrict__ perm = a.perm[g];
    const int*  __restrict__ rp   = a.rp[g];
    const int F = 64 * C;
    const int e0 = rp[row], e1 = rp[row + 1];
    float acc[C] = {};
    const int laneoff = lane * C;

    for (int eb = e0; eb < e1; eb += 64) {
        int idx = eb + lane;
        int myS = 0; int myW = 0;
        if (idx < e1) { int2 rec = perm[idx]; myS = rec.x; myW = rec.y; }
        int m = min(64, e1 - eb);
        for (int j0 = 0; j0 < m; j0 += 8) {
            #pragma unroll
            for (int u = 0; u < 8; ++u) {
                int j = j0 + u;   // padded lanes carry w=0
                int   s = __builtin_amdgcn_readlane(myS, j);
                float w = __int_as_float(__builtin_amdgcn_readlane(myW, j));
                const f16* xr = x + (size_t)((uint)s * (uint)F) + laneoff;
                union { uint2 u2; f16 h[4]; } cv;
                cv.u2 = *reinterpret_cast<const uint2*>(xr);
                acc[0] = fmaf((float)cv.h[0], w, acc[0]);
                acc[1] = fmaf((float)cv.h[1], w, acc[1]);
                acc[2] = fmaf((float)cv.h[2], w, acc[2]);
                acc[3] = fmaf((float)cv.h[3], w, acc[3]);
            }
        }
    }

    #pragma unroll
    for (int c = 0; c < C; ++c) {
        float v = acc[c] + bias[laneoff + c];
        acc[c] = fmaxf(v, 0.f);
    }
    *reinterpret_cast<ushort4*>(a.outh[g] + (size_t)row * F + laneoff) =
        make_ushort4(f2h_bits(acc[0]), f2h_bits(acc[1]), f2h_bits(acc[2]), f2h_bits(acc[3]));
}

// ---------------------------------------------------------------------------
// L2 SpMM (single graph): out = spmm + bias -> f16 + f32 outputs. F = 128.
// ---------------------------------------------------------------------------
__global__ __launch_bounds__(256) void spmm_l2_f16(
    const f16* __restrict__ x,
    const int2* __restrict__ perm,
    const int* __restrict__ row_ptr, const float* __restrict__ bias,
    ushort* __restrict__ out_h, float* __restrict__ out_f, int n)
{
    const int wave = threadIdx.x >> 6, lane = threadIdx.x & 63;
    const int row = blockIdx.x * 4 + wave;
    if (row >= n) return;
    const int F = 128;
    const int e0 = row_ptr[row], e1 = row_ptr[row + 1];
    float acc[2] = {};
    const int laneoff = lane * 2;

    for (int eb = e0; eb < e1; eb += 64) {
        int idx = eb + lane;
        int myS = 0; int myW = 0;
        if (idx < e1) { int2 rec = perm[idx]; myS = rec.x; myW = rec.y; }
        int m = min(64, e1 - eb);
        for (int j0 = 0; j0 < m; j0 += 8) {
            #pragma unroll
            for (int u = 0; u < 8; ++u) {
                int j = j0 + u;
                int   s = __builtin_amdgcn_readlane(myS, j);
                float w = __int_as_float(__builtin_amdgcn_readlane(myW, j));
                union { uint u1; f16 h[2]; } cv;
                cv.u1 = *reinterpret_cast<const uint*>(x + (size_t)((uint)s * (uint)F) + laneoff);
                acc[0] = fmaf((float)cv.h[0], w, acc[0]);
                acc[1] = fmaf((float)cv.h[1], w, acc[1]);
            }
        }
    }

    acc[0] += bias[laneoff];
    acc[1] += bias[laneoff + 1];
    size_t ob = (size_t)row * F + laneoff;
    *reinterpret_cast<float2*>(out_f + ob) = make_float2(acc[0], acc[1]);
    *reinterpret_cast<ushort2*>(out_h + ob) = make_ushort2(f2h_bits(acc[0]), f2h_bits(acc[1]));
}

// ---------------------------------------------------------------------------
// f16 MFMA GEMM: C[M,N] = A[M,K] @ Bt[N,K]^T, 128x128 tile, BK=32, 4 waves.
// SWAP: bn from blockIdx.x (N fastest -> A-tile reuse across N-blocks).
// CVTA: A is f32, converted inline. FUSE: A = concat([A,A2]), each [M,128].
// ---------------------------------------------------------------------------
template<bool SWAP, bool CVTA, bool FUSE, bool RELU, bool BIAS, bool F32OUT>
__global__ __launch_bounds__(256) void gemm_mfma(
    const void* __restrict__ Av, const ushort* __restrict__ A2,
    const ushort* __restrict__ Bt, const float* __restrict__ bias,
    ushort* __restrict__ Ch, float* __restrict__ Cf,
    int M, int N, int K)
{
    __shared__ ushort Asb[128 * 32];
    __shared__ ushort Bsb[128 * 32];
    const int tid = threadIdx.x;
    const int lane = tid & 63, wave = tid >> 6;
    const int wr = wave >> 1, wc = wave & 1;
    const int bm = (SWAP ? blockIdx.y : blockIdx.x) * 128;
    const int bn = (SWAP ? blockIdx.x : blockIdx.y) * 128;

    f32x4 acc[4][4] = {};

    for (int k0 = 0; k0 < K; k0 += 32) {
        #pragma unroll
        for (int h = 0; h < 2; ++h) {
            int slot = tid + 256 * h;
            int r = slot >> 2, cb = slot & 3;
            int row = bm + r;
            uint4 v = make_uint4(0, 0, 0, 0);
            if (row < M) {
                int kk = k0 + cb * 8;
                if (CVTA) {
                    const float* Af = (const float*)Av;
                    float4 lo = *reinterpret_cast<const float4*>(Af + (size_t)row * K + kk);
                    float4 hi = *reinterpret_cast<const float4*>(Af + (size_t)row * K + kk + 4);
                    ushort h8[8] = { f2h_bits(lo.x), f2h_bits(lo.y), f2h_bits(lo.z), f2h_bits(lo.w),
                                     f2h_bits(hi.x), f2h_bits(hi.y), f2h_bits(hi.z), f2h_bits(hi.w) };
                    v = *reinterpret_cast<const uint4*>(h8);
                } else if (FUSE) {
                    const ushort* Ap = (kk < 128) ? (const ushort*)Av : A2;
                    v = *reinterpret_cast<const uint4*>(Ap + (size_t)row * 128 + (kk & 127));
                } else {
                    v = *reinterpret_cast<const uint4*>((const ushort*)Av + (size_t)row * K + kk);
                }
            }
            int scb = cb ^ ((r >> 1) & 3);
            *reinterpret_cast<uint4*>(&Asb[r * 32 + scb * 8]) = v;
        }
        #pragma unroll
        for (int h = 0; h < 2; ++h) {
            int slot = tid + 256 * h;
            int r = slot >> 2, cb = slot & 3;
            uint4 v = *reinterpret_cast<const uint4*>(Bt + (size_t)(bn + r) * K + k0 + cb * 8);
            int scb = cb ^ ((r >> 1) & 3);
            *reinterpret_cast<uint4*>(&Bsb[r * 32 + scb * 8]) = v;
        }
        __syncthreads();

        f16x8 fa[4], fb[4];
        #pragma unroll
        for (int i = 0; i < 4; ++i) {
            int r = wr * 64 + i * 16 + (lane & 15);
            int scb = (lane >> 4) ^ ((r >> 1) & 3);
            fa[i] = *reinterpret_cast<const f16x8*>(&Asb[r * 32 + scb * 8]);
        }
        #pragma unroll
        for (int j = 0; j < 4; ++j) {
            int r = wc * 64 + j * 16 + (lane & 15);
            int scb = (lane >> 4) ^ ((r >> 1) & 3);
            fb[j] = *reinterpret_cast<const f16x8*>(&Bsb[r * 32 + scb * 8]);
        }
        #pragma unroll
        for (int i = 0; i < 4; ++i)
            #pragma unroll
            for (int j = 0; j < 4; ++j)
                acc[i][j] = __builtin_amdgcn_mfma_f32_16x16x32_f16(fa[i], fb[j], acc[i][j], 0, 0, 0);
        __syncthreads();
    }

    #pragma unroll
    for (int i = 0; i < 4; ++i) {
        #pragma unroll
        for (int r4 = 0; r4 < 4; ++r4) {
            int row = bm + wr * 64 + i * 16 + (lane >> 4) * 4 + r4;
            if (row >= M) continue;
            #pragma unroll
            for (int j = 0; j < 4; ++j) {
                int col = bn + wc * 64 + j * 16 + (lane & 15);
                float v = acc[i][j][r4];
                if (BIAS) v += bias[col];
                if (RELU) v = fmaxf(v, 0.f);
                if (F32OUT) Cf[(size_t)row * N + col] = v;
                else        Ch[(size_t)row * N + col] = f2h_bits(v);
            }
        }
    }
}

// ---------------------------------------------------------------------------
// Orchestration
// ---------------------------------------------------------------------------
extern "C" void kernel_launch(void* const* d_in, const int* in_sizes, int n_in,
                              void* d_out, int out_size, void* d_ws, size_t ws_size,
                              hipStream_t stream) {
    const float* Xd       = (const float*)d_in[0];
    const int*   eid_sim  = (const int*)  d_in[1];
    const float* wd_sim   = (const float*)d_in[2];
    const int*   eid_feat = (const int*)  d_in[3];
    const float* wd_feat  = (const float*)d_in[4];
    const float* Xs       = (const float*)d_in[5];
    const int*   eis_sim  = (const int*)  d_in[6];
    const float* ws_sim   = (const float*)d_in[7];
    const int*   eis_feat = (const int*)  d_in[8];
    const float* ws_feat  = (const float*)d_in[9];
    const float* W1d = (const float*)d_in[10]; const float* b1d = (const float*)d_in[11];
    const float* W2d = (const float*)d_in[12]; const float* b2d = (const float*)d_in[13];
    const float* W1s = (const float*)d_in[14]; const float* b1s = (const float*)d_in[15];
    const float* W2s = (const float*)d_in[16]; const float* b2s = (const float*)d_in[17];
    const float* Wfd = (const float*)d_in[18]; const float* bfd = (const float*)d_in[19];
    const float* Wfs = (const float*)d_in[20]; const float* bfs = (const float*)d_in[21];

    const int Fd = 256, H1 = 256, H2 = 128;
    const int Nd = in_sizes[0] / Fd;
    const int Ns = in_sizes[5] / Fd;
    const int Ed = in_sizes[2];
    const int Es = in_sizes[7];

    float* out    = (float*)d_out;
    float* o_emb1 = out;
    float* o_emb2 = o_emb1 + (size_t)Nd * H2;
    float* o_e1s  = o_emb2 + (size_t)Ns * H2;
    float* o_e1f  = o_e1s  + (size_t)Nd * H2;
    float* o_e2s  = o_e1f  + (size_t)Nd * H2;
    float* o_e2f  = o_e2s  + (size_t)Ns * H2;

    char* p = (char*)d_ws;
    auto alloc = [&](size_t bytes) { char* q = p; p += (bytes + 255) & ~(size_t)255; return q; };
    ushort* xw1   = (ushort*)alloc((size_t)Nd * 256 * 2);
    ushort* hbuf0 = (ushort*)alloc((size_t)Nd * 256 * 2);
    ushort* hbuf1 = (ushort*)alloc((size_t)Nd * 256 * 2);
    ushort* tbuf0 = (ushort*)alloc((size_t)Nd * 128 * 2);
    ushort* tbuf1 = (ushort*)alloc((size_t)Nd * 128 * 2);
    ushort* W1dt  = (ushort*)alloc(256 * 256 * 2);
    ushort* W2dt  = (ushort*)alloc(256 * 128 * 2);
    ushort* Wfdt  = (ushort*)alloc(256 * 128 * 2);
    ushort* W1st  = (ushort*)alloc(256 * 256 * 2);
    ushort* W2st  = (ushort*)alloc(256 * 128 * 2);
    ushort* Wfst  = (ushort*)alloc(256 * 128 * 2);
    int2*   perm0 = (int2*)alloc((size_t)Ed * 8);
    int2*   perm1 = (int2*)alloc((size_t)Ed * 8);
    int2*   perm2 = (int2*)alloc((size_t)Es * 8);
    int2*   perm3 = (int2*)alloc((size_t)Es * 8);
    int*    rp0   = (int*) alloc((size_t)(Nd + 1) * 4);
    int*    rp1   = (int*) alloc((size_t)(Nd + 1) * 4);
    int*    rp2   = (int*) alloc((size_t)(Ns + 1) * 4);
    int*    rp3   = (int*) alloc((size_t)(Ns + 1) * 4);
    int*    bcounts = (int*)alloc(4 * 512 * 4);
    int*    bbase   = (int*)alloc(4 * 513 * 4);
    int*    bcursor = (int*)alloc(4 * 512 * 4);
    // aliases: bst over hbuf0+hbuf1 (dead during CSR build; 2(Ed+Es)*8 <= 2*Nd*512B)
    int2*   bst  = (int2*)hbuf0;
    // es/ef over xw1 (xw1 dead after the branch's L1 spmm pair)
    ushort* es_h = xw1;
    ushort* ef_h = xw1 + (size_t)Nd * 128;

    // ---- batched weight transposes ----
    {
        T6 a;
        a.s[0] = W1d; a.s[1] = W2d; a.s[2] = Wfd; a.s[3] = W1s; a.s[4] = W2s; a.s[5] = Wfs;
        a.d[0] = W1dt; a.d[1] = W2dt; a.d[2] = Wfdt; a.d[3] = W1st; a.d[4] = W2st; a.d[5] = Wfst;
        a.N[0] = 256; a.N[1] = 128; a.N[2] = 128; a.N[3] = 256; a.N[4] = 128; a.N[5] = 128;
        transpose6_k<<<dim3(8, 8, 6), 256, 0, stream>>>(a);
    }

    // ---- batched CSR build for all 4 graphs (runs before hbuf is live) ----
    G4 a;
    a.g[0] = { eid_sim,  wd_sim,  Ed, Nd, (Nd + 255) >> 8, 0,           rp0, perm0 };
    a.g[1] = { eid_feat, wd_feat, Ed, Nd, (Nd + 255) >> 8, Ed,          rp1, perm1 };
    a.g[2] = { eis_sim,  ws_sim,  Es, Ns, (Ns + 255) >> 8, 2 * Ed,      rp2, perm2 };
    a.g[3] = { eis_feat, ws_feat, Es, Ns, (Ns + 255) >> 8, 2 * Ed + Es, rp3, perm3 };
    {
        const int maxEB = (Ed + 4095) / 4096;
        const int maxNB = (Nd + 255) >> 8;
        hipMemsetAsync(bcounts, 0, 4 * 512 * 4, stream);
        hist_b<<<dim3(maxEB, 4), 256, 0, stream>>>(a, bcounts);
        scan_b<<<4, 256, 0, stream>>>(a, bcounts, bbase, bcursor);
        scatter_b<<<dim3(maxEB, 4), 256, 0, stream>>>(a, bcursor, bst);
        finalize_b<<<dim3(maxNB, 4), 256, 0, stream>>>(a, bbase, bst);
    }

    // ---- per-branch compute ----
    auto branch = [&](const float* X, int n,
                      const int2* pA, const int* rpA,
                      const int2* pB, const int* rpB,
                      const ushort* W1t, const float* b1,
                      const ushort* W2t, const float* b2,
                      const ushort* Wft, const float* bfu,
                      float* o_sim, float* o_feat, float* o_emb) {
        const int Mb = (n + 127) / 128;
        // xw1 = f16(X) @ W1 ; N-fastest grid so the A f32 tile is read once hot
        gemm_mfma<true, true, false, false, false, false><<<dim3(2, Mb), 256, 0, stream>>>(
            X, nullptr, W1t, nullptr, xw1, nullptr, n, 256, 256);
        // both graphs gather from the same xw1 table in one dispatch
        PairDesc pd;
        pd.perm[0] = pA; pd.perm[1] = pB;
        pd.rp[0] = rpA;  pd.rp[1] = rpB;
        pd.outh[0] = hbuf0; pd.outh[1] = hbuf1;
        spmm_pair_f16<4><<<dim3((n + 3) / 4, 2), 256, 0, stream>>>(
            (const f16*)xw1, pd, b1, n);
        // t_g = h_g @ W2 ; then L2 spmm per graph (separate tables)
        gemm_mfma<false, false, false, false, false, false><<<dim3(Mb, 1), 256, 0, stream>>>(
            hbuf0, nullptr, W2t, nullptr, tbuf0, nullptr, n, 128, 256);
        gemm_mfma<false, false, false, false, false, false><<<dim3(Mb, 1), 256, 0, stream>>>(
            hbuf1, nullptr, W2t, nullptr, tbuf1, nullptr, n, 128, 256);
        spmm_l2_f16<<<(n + 3) / 4, 256, 0, stream>>>(
            (const f16*)tbuf0, pA, rpA, b2, es_h, o_sim, n);
        spmm_l2_f16<<<(n + 3) / 4, 256, 0, stream>>>(
            (const f16*)tbuf1, pB, rpB, b2, ef_h, o_feat, n);
        // fusion: relu(concat(es,ef) @ Wf + bf)
        gemm_mfma<false, false, true, true, true, true><<<dim3(Mb, 1), 256, 0, stream>>>(
            es_h, ef_h, Wft, bfu, nullptr, o_emb, n, 128, 256);
    };

    branch(Xd, Nd, perm0, rp0, perm1, rp1,
           W1dt, b1d, W2dt, b2d, Wfdt, bfd, o_e1s, o_e1f, o_emb1);
    branch(Xs, Ns, perm2, rp2, perm3, rp3,
           W1st, b1s, W2st, b2s, Wfst, bfs, o_e2s, o_e2f, o_emb2);
}